// Round 30
// baseline (352.935 us; speedup 1.0000x reference)
//
#include <hip/hip_runtime.h>
#include <hip/hip_bf16.h>

#define NN 50000
#define NE 600000
#define HD 128
#define NBLK 196                     // ceil((NN+1)/256)
#define NTILES 3125                  // NN/16 exactly
#define GPERS 782                    // persistent GEMM grid; 782*4 >= 3125
#define LDT 136                      // padded LDS row stride (ushorts)

typedef unsigned short ushort_t;
typedef __attribute__((ext_vector_type(8))) short short8v;   // 8 bf16 (4 VGPRs)
typedef __attribute__((ext_vector_type(4))) float f32x4;

__device__ __forceinline__ float sigmoidf_(float x){
  return __builtin_amdgcn_rcpf(1.f + __expf(-x));   // raw v_rcp: <=1 ulp
}

__device__ __forceinline__ ushort_t f2bf(float f){
  unsigned int u = __float_as_uint(f);
  unsigned int r = (u + 0x7FFFu + ((u >> 16) & 1u)) >> 16;   // RNE
  return (ushort_t)r;
}

__device__ __forceinline__ float bflo(unsigned u){ return __uint_as_float(u << 16); }
__device__ __forceinline__ float bfhi(unsigned u){ return __uint_as_float(u & 0xFFFF0000u); }

// ---------------- diagnostic scalar write (env tripwire) ----------------
__global__ void write_scalar_kernel(float* __restrict__ p, float v){ p[0] = v; }

// ------- edge_index decode with per-block dtype detection (+ dst histogram) --------
__global__ __launch_bounds__(256) void extract_kernel(const void* __restrict__ ei,
    int* __restrict__ srcW, int* __restrict__ dstW, int* __restrict__ counts){
  __shared__ int hasNZ;
  const int e = blockIdx.x*256 + threadIdx.x;
  if (threadIdx.x == 0) hasNZ = 0;
  __syncthreads();
  if (e < NE){
    const unsigned* w = (const unsigned*)ei;
    if (w[2*(size_t)e + 1] != 0u) hasNZ = 1;   // benign race: all writers store 1
  }
  __syncthreads();
  const bool is64 = (hasNZ == 0);
  if (e < NE){
    int s, d;
    if (is64){
      const long long* p = (const long long*)ei;
      s = (int)p[e]; d = (int)p[NE + e];
    } else {
      const int* p = (const int*)ei;
      s = p[e]; d = p[NE + e];
    }
    srcW[e] = s; dstW[e] = d;
    atomicAdd(&counts[d], 1);
  }
}

// ---------------- scan: partial sums, then fused offset+local scan ----------------
__global__ __launch_bounds__(256) void scanA_kernel(const int* __restrict__ counts,
                                                    int* __restrict__ partial){
  __shared__ int s[256];
  const int t = threadIdx.x;
  const int idx = blockIdx.x*256 + t;
  s[t] = (idx < NN) ? counts[idx] : 0;
  __syncthreads();
  for (int off = 128; off > 0; off >>= 1){
    if (t < off) s[t] += s[t + off];
    __syncthreads();
  }
  if (t == 0) partial[blockIdx.x] = s[0];
}

__global__ __launch_bounds__(256) void scanC_kernel(const int* __restrict__ counts,
    const int* __restrict__ partial, int* __restrict__ row_start, int* __restrict__ cursor){
  __shared__ int s[256];
  __shared__ int baseS;
  const int t = threadIdx.x;
  {
    int v = (t < NBLK && t < blockIdx.x) ? partial[t] : 0;
    s[t] = v;
    __syncthreads();
    for (int off = 128; off > 0; off >>= 1){
      if (t < off) s[t] += s[t + off];
      __syncthreads();
    }
    if (t == 0) baseS = s[0];
    __syncthreads();
  }
  const int base = baseS;
  __syncthreads();                     // s[] reuse
  const int idx = blockIdx.x*256 + t;
  const int c = (idx < NN) ? counts[idx] : 0;
  s[t] = c;
  __syncthreads();
  for (int off = 1; off < 256; off <<= 1){
    int add = (t >= off) ? s[t - off] : 0;
    __syncthreads();
    s[t] += add;
    __syncthreads();
  }
  const int excl = base + s[t] - c;
  if (idx < NN){ row_start[idx] = excl; cursor[idx] = excl; }
  else if (idx == NN){ row_start[NN] = excl; }
}

// fill: also writes CSR-ordered src (srcS) so msg needs no eids->srcI indirection
__global__ void fill_kernel(const int* __restrict__ dstI, const int* __restrict__ srcI,
                            int* __restrict__ cursor, int* __restrict__ eids,
                            int* __restrict__ srcS){
  int e = blockIdx.x*256 + threadIdx.x;
  if (e < NE){
    int p = atomicAdd(&cursor[dstI[e]], 1);
    eids[p] = e;
    srcS[p] = srcI[e];
  }
}

// ------- weight convert+transpose, all 6 matrices: Wt[n][k] = bf16(W[k][n]) --------
__global__ __launch_bounds__(256) void wcvt_all_kernel(const float* __restrict__ Wemb,
    const float* __restrict__ Wgnn, const float* __restrict__ Wm1,
    ushort_t* __restrict__ WtAll){
  const int idx = blockIdx.x*256 + threadIdx.x;   // 6*16384
  const int m = idx >> 14;                        // 0..5
  const int r = idx & 16383;
  const int k = r >> 7, n = r & 127;
  const float* W = (m == 0) ? Wemb : (m <= 3) ? (Wgnn + (size_t)(m-1)*16384)
                                              : (Wm1  + (size_t)(m-4)*16384);
  WtAll[(size_t)m*16384 + n*HD + k] = f2bf(W[r]);
}

// ====== persistent fused GEMM with A-prefetch across the tile loop ======
template<int F32A, int DOUV>
__global__ __launch_bounds__(256, 3) void gemm_fused(const void* __restrict__ inP,
    const ushort_t* __restrict__ Wt, const float* __restrict__ bias,
    float* __restrict__ outF, ushort_t* __restrict__ outB,
    const ushort_t* __restrict__ WtU, const ushort_t* __restrict__ WtV,
    const float* __restrict__ biasU, ushort_t* __restrict__ outU,
    ushort_t* __restrict__ outV)
{
  __shared__ ushort_t hT[16*LDT];             // 4.25 KB: block's 16x128 bf16 h tile
  const int cq   = threadIdx.x >> 6;          // col-quarter 0..3
  const int lane = threadIdx.x & 63;
  const int fr = lane & 15;
  const int fq = lane >> 4;
  short8v bh[4][2];
  #pragma unroll
  for (int ks = 0; ks < 4; ++ks)
    #pragma unroll
    for (int tcl = 0; tcl < 2; ++tcl)
      bh[ks][tcl] = *(const short8v*)(Wt + (size_t)((cq*2+tcl)*16 + fr)*HD + ks*32 + fq*8);
  short8v bu[4][2], bv[4][2];
  if (DOUV){
    #pragma unroll
    for (int ks = 0; ks < 4; ++ks)
      #pragma unroll
      for (int tcl = 0; tcl < 2; ++tcl){
        bu[ks][tcl] = *(const short8v*)(WtU + (size_t)((cq*2+tcl)*16 + fr)*HD + ks*32 + fq*8);
        bv[ks][tcl] = *(const short8v*)(WtV + (size_t)((cq*2+tcl)*16 + fr)*HD + ks*32 + fq*8);
      }
  }
  float bb[2], bub[2];
  #pragma unroll
  for (int tcl = 0; tcl < 2; ++tcl){
    const int col = (cq*2 + tcl)*16 + fr;
    bb[tcl]  = bias ? bias[col] : 0.f;
    bub[tcl] = DOUV ? biasU[col] : 0.f;
  }

  float4  aF[8];
  short8v aB[4];
  {
    const int arow = blockIdx.x*16 + fr;
    if (F32A){
      const float* in = (const float*)inP;
      #pragma unroll
      for (int ks = 0; ks < 4; ++ks){
        aF[2*ks]   = *(const float4*)(in + (size_t)arow*HD + ks*32 + fq*8);
        aF[2*ks+1] = *(const float4*)(in + (size_t)arow*HD + ks*32 + fq*8 + 4);
      }
    } else {
      const ushort_t* inB = (const ushort_t*)inP;
      #pragma unroll
      for (int ks = 0; ks < 4; ++ks)
        aB[ks] = *(const short8v*)(inB + (size_t)arow*HD + ks*32 + fq*8);
    }
  }

  #pragma unroll
  for (int it = 0; it < 4; ++it){
    const int tile = blockIdx.x + it*GPERS;
    if (tile >= NTILES) break;                 // block-uniform
    const int row0 = tile*16;
    f32x4 acc0 = (f32x4)0.0f, acc1 = (f32x4)0.0f;
    #pragma unroll
    for (int ks = 0; ks < 4; ++ks){
      short8v af;
      if (F32A){
        const float4 a0 = aF[2*ks], a1 = aF[2*ks+1];
        af[0]=(short)f2bf(a0.x); af[1]=(short)f2bf(a0.y);
        af[2]=(short)f2bf(a0.z); af[3]=(short)f2bf(a0.w);
        af[4]=(short)f2bf(a1.x); af[5]=(short)f2bf(a1.y);
        af[6]=(short)f2bf(a1.z); af[7]=(short)f2bf(a1.w);
      } else {
        af = aB[ks];
      }
      acc0 = __builtin_amdgcn_mfma_f32_16x16x32_bf16(af, bh[ks][0], acc0, 0, 0, 0);
      acc1 = __builtin_amdgcn_mfma_f32_16x16x32_bf16(af, bh[ks][1], acc1, 0, 0, 0);
    }
    {
      const int ntile = tile + GPERS;
      if (ntile < NTILES){
        const int arow = ntile*16 + fr;
        if (F32A){
          const float* in = (const float*)inP;
          #pragma unroll
          for (int ks = 0; ks < 4; ++ks){
            aF[2*ks]   = *(const float4*)(in + (size_t)arow*HD + ks*32 + fq*8);
            aF[2*ks+1] = *(const float4*)(in + (size_t)arow*HD + ks*32 + fq*8 + 4);
          }
        } else {
          const ushort_t* inB = (const ushort_t*)inP;
          #pragma unroll
          for (int ks = 0; ks < 4; ++ks)
            aB[ks] = *(const short8v*)(inB + (size_t)arow*HD + ks*32 + fq*8);
        }
      }
    }
    #pragma unroll
    for (int tcl = 0; tcl < 2; ++tcl){
      const f32x4 a = tcl ? acc1 : acc0;
      const int col = (cq*2 + tcl)*16 + fr;
      #pragma unroll
      for (int j = 0; j < 4; ++j){
        const int r = row0 + fq*4 + j;
        float x = fmaxf(a[j] + bb[tcl], 0.f);  // all h GEMMs use relu
        const ushort_t xb = f2bf(x);
        if (DOUV) hT[(fq*4 + j)*LDT + col] = xb;
        if (outF) outF[(size_t)r*HD + col] = x;
        if (outB) outB[(size_t)r*HD + col] = xb;
      }
    }
    if (DOUV){
      __syncthreads();
      f32x4 aU0 = (f32x4)0.0f, aU1 = (f32x4)0.0f;
      f32x4 aV0 = (f32x4)0.0f, aV1 = (f32x4)0.0f;
      #pragma unroll
      for (int ks = 0; ks < 4; ++ks){
        const short8v af = *(const short8v*)(hT + fr*LDT + ks*32 + fq*8);
        aU0 = __builtin_amdgcn_mfma_f32_16x16x32_bf16(af, bu[ks][0], aU0, 0, 0, 0);
        aU1 = __builtin_amdgcn_mfma_f32_16x16x32_bf16(af, bu[ks][1], aU1, 0, 0, 0);
        aV0 = __builtin_amdgcn_mfma_f32_16x16x32_bf16(af, bv[ks][0], aV0, 0, 0, 0);
        aV1 = __builtin_amdgcn_mfma_f32_16x16x32_bf16(af, bv[ks][1], aV1, 0, 0, 0);
      }
      #pragma unroll
      for (int tcl = 0; tcl < 2; ++tcl){
        const f32x4 u = tcl ? aU1 : aU0;
        const f32x4 v = tcl ? aV1 : aV0;
        const int col = (cq*2 + tcl)*16 + fr;
        #pragma unroll
        for (int j = 0; j < 4; ++j){
          const int r = row0 + fq*4 + j;
          outU[(size_t)r*HD + col] = f2bf(u[j] + bub[tcl]);
          outV[(size_t)r*HD + col] = f2bf(v[j]);
        }
      }
      __syncthreads();                         // protect hT for next iteration
    }
  }
}

// ---------------- final-layer GEMM (bf16 A -> f32 out, no UV), persistent ----------
__global__ __launch_bounds__(256, 3) void gemm_final(const ushort_t* __restrict__ inB,
    const ushort_t* __restrict__ Wt, const float* __restrict__ bias,
    float* __restrict__ outF)
{
  const int cq   = threadIdx.x >> 6;
  const int lane = threadIdx.x & 63;
  const int fr = lane & 15;
  const int fq = lane >> 4;
  short8v bh[4][2];
  #pragma unroll
  for (int ks = 0; ks < 4; ++ks)
    #pragma unroll
    for (int tcl = 0; tcl < 2; ++tcl)
      bh[ks][tcl] = *(const short8v*)(Wt + (size_t)((cq*2+tcl)*16 + fr)*HD + ks*32 + fq*8);
  float bb[2];
  #pragma unroll
  for (int tcl = 0; tcl < 2; ++tcl) bb[tcl] = bias[(cq*2 + tcl)*16 + fr];
  short8v aB[4];
  {
    const int arow = blockIdx.x*16 + fr;
    #pragma unroll
    for (int ks = 0; ks < 4; ++ks)
      aB[ks] = *(const short8v*)(inB + (size_t)arow*HD + ks*32 + fq*8);
  }
  #pragma unroll
  for (int it = 0; it < 4; ++it){
    const int tile = blockIdx.x + it*GPERS;
    if (tile >= NTILES) break;
    const int row0 = tile*16;
    f32x4 acc0 = (f32x4)0.0f, acc1 = (f32x4)0.0f;
    #pragma unroll
    for (int ks = 0; ks < 4; ++ks){
      acc0 = __builtin_amdgcn_mfma_f32_16x16x32_bf16(aB[ks], bh[ks][0], acc0, 0, 0, 0);
      acc1 = __builtin_amdgcn_mfma_f32_16x16x32_bf16(aB[ks], bh[ks][1], acc1, 0, 0, 0);
    }
    const int ntile = tile + GPERS;
    if (ntile < NTILES){
      const int arow = ntile*16 + fr;
      #pragma unroll
      for (int ks = 0; ks < 4; ++ks)
        aB[ks] = *(const short8v*)(inB + (size_t)arow*HD + ks*32 + fq*8);
    }
    #pragma unroll
    for (int tcl = 0; tcl < 2; ++tcl){
      const f32x4 a = tcl ? acc1 : acc0;
      const int col = (cq*2 + tcl)*16 + fr;
      #pragma unroll
      for (int j = 0; j < 4; ++j){
        const int r = row0 + fq*4 + j;
        outF[(size_t)r*HD + col] = fmaxf(a[j] + bb[tcl], 0.f);
      }
    }
  }
}

// ------- fused mask+msg: 1 node / 128-thread block, 2 waves x 4 groups, stride 8 ----
template<int MASKW>
__global__ __launch_bounds__(128) void mask_msg_kernel(
    const ushort_t* __restrict__ U, const ushort_t* __restrict__ V,
    const ushort_t* __restrict__ hB,        // gather source + own-row base (bf16)
    ushort_t* __restrict__ hB2,             // out: bf16 of post-msg h
    const int* __restrict__ srcS, const int* __restrict__ eidS,
    const int* __restrict__ row_start,
    const float* __restrict__ Wm2, const float* __restrict__ bm2,
    float* __restrict__ maskOut)            // used only when MASKW
{
  __shared__ float ws[16][9];               // padded: conflict-free cross-wave combine
  const int v = blockIdx.x;
  const int wid  = threadIdx.x >> 6;        // 0..1
  const int lane = threadIdx.x & 63;
  const int g8  = wid*4 + (lane >> 4);      // edge group 0..7
  const int sub = lane & 15;                // lane in group
  const float4 wA = ((const float4*)Wm2)[sub*2];      // cols sub*8..+3
  const float4 wB = ((const float4*)Wm2)[sub*2+1];    // cols sub*8+4..+7
  const float b2 = bm2[0];
  const uint4 vv = ((const uint4*)(V + (size_t)v*HD))[sub];
  float a0=0.f,a1=0.f,a2=0.f,a3=0.f,a4=0.f,a5=0.f,a6=0.f,a7=0.f;
  const int beg = row_start[v], end = row_start[v+1];
  int idx = beg + g8;
  uint4 uu = make_uint4(0,0,0,0), hh = make_uint4(0,0,0,0);
  int e0 = 0;
  if (idx < end){
    const int s = srcS[idx];
    if (MASKW) e0 = eidS[idx];
    uu = ((const uint4*)(U  + (size_t)s*HD))[sub];
    hh = ((const uint4*)(hB + (size_t)s*HD))[sub];
  }
  while (idx < end){
    const int nidx = idx + 8;
    uint4 uuN = make_uint4(0,0,0,0), hhN = make_uint4(0,0,0,0);
    int eN = 0;
    if (nidx < end){
      const int sn = srcS[nidx];
      if (MASKW) eN = eidS[nidx];
      uuN = ((const uint4*)(U  + (size_t)sn*HD))[sub];
      hhN = ((const uint4*)(hB + (size_t)sn*HD))[sub];
    }
    float p;
    p = fmaxf(bflo(uu.x)+bflo(vv.x), 0.f) * wA.x;
    p = fmaf(fmaxf(bfhi(uu.x)+bfhi(vv.x), 0.f), wA.y, p);
    p = fmaf(fmaxf(bflo(uu.y)+bflo(vv.y), 0.f), wA.z, p);
    p = fmaf(fmaxf(bfhi(uu.y)+bfhi(vv.y), 0.f), wA.w, p);
    p = fmaf(fmaxf(bflo(uu.z)+bflo(vv.z), 0.f), wB.x, p);
    p = fmaf(fmaxf(bfhi(uu.z)+bfhi(vv.z), 0.f), wB.y, p);
    p = fmaf(fmaxf(bflo(uu.w)+bflo(vv.w), 0.f), wB.z, p);
    p = fmaf(fmaxf(bfhi(uu.w)+bfhi(vv.w), 0.f), wB.w, p);
    p += __shfl_xor(p, 1, 64);
    p += __shfl_xor(p, 2, 64);
    p += __shfl_xor(p, 4, 64);
    p += __shfl_xor(p, 8, 64);
    const float imp = sigmoidf_(p + b2);
    const float mk  = sigmoidf_((imp - 0.4f) * 2.0f);
    if (MASKW && sub == 0) maskOut[e0] = mk;
    a0 = fmaf(mk, bflo(hh.x), a0);
    a1 = fmaf(mk, bfhi(hh.x), a1);
    a2 = fmaf(mk, bflo(hh.y), a2);
    a3 = fmaf(mk, bfhi(hh.y), a3);
    a4 = fmaf(mk, bflo(hh.z), a4);
    a5 = fmaf(mk, bfhi(hh.z), a5);
    a6 = fmaf(mk, bflo(hh.w), a6);
    a7 = fmaf(mk, bfhi(hh.w), a7);
    uu = uuN; hh = hhN; e0 = eN; idx = nidx;
  }
  // intra-wave combine over the wave's 4 groups
  a0 += __shfl_xor(a0, 16, 64); a0 += __shfl_xor(a0, 32, 64);
  a1 += __shfl_xor(a1, 16, 64); a1 += __shfl_xor(a1, 32, 64);
  a2 += __shfl_xor(a2, 16, 64); a2 += __shfl_xor(a2, 32, 64);
  a3 += __shfl_xor(a3, 16, 64); a3 += __shfl_xor(a3, 32, 64);
  a4 += __shfl_xor(a4, 16, 64); a4 += __shfl_xor(a4, 32, 64);
  a5 += __shfl_xor(a5, 16, 64); a5 += __shfl_xor(a5, 32, 64);
  a6 += __shfl_xor(a6, 16, 64); a6 += __shfl_xor(a6, 32, 64);
  a7 += __shfl_xor(a7, 16, 64); a7 += __shfl_xor(a7, 32, 64);
  // cross-wave combine via LDS (wave0 -> wave1)
  if (wid == 0 && lane < 16){
    ws[sub][0]=a0; ws[sub][1]=a1; ws[sub][2]=a2; ws[sub][3]=a3;
    ws[sub][4]=a4; ws[sub][5]=a5; ws[sub][6]=a6; ws[sub][7]=a7;
  }
  __syncthreads();
  if (wid == 1 && lane < 16){
    a0 += ws[sub][0]; a1 += ws[sub][1]; a2 += ws[sub][2]; a3 += ws[sub][3];
    a4 += ws[sub][4]; a5 += ws[sub][5]; a6 += ws[sub][6]; a7 += ws[sub][7];
    const uint4 hrow = ((const uint4*)(hB + (size_t)v*HD))[sub];  // own row, bf16
    const float x0 = bflo(hrow.x) + a0, x1 = bfhi(hrow.x) + a1;
    const float x2 = bflo(hrow.y) + a2, x3 = bfhi(hrow.y) + a3;
    const float x4 = bflo(hrow.z) + a4, x5 = bfhi(hrow.z) + a5;
    const float x6 = bflo(hrow.w) + a6, x7 = bfhi(hrow.w) + a7;
    ushort4 p0, p1;
    p0.x = f2bf(x0); p0.y = f2bf(x1); p0.z = f2bf(x2); p0.w = f2bf(x3);
    p1.x = f2bf(x4); p1.y = f2bf(x5); p1.z = f2bf(x6); p1.w = f2bf(x7);
    ushort4* hb2row = (ushort4*)(hB2 + (size_t)v*HD) + sub*2;
    hb2row[0] = p0;
    hb2row[1] = p1;
  }
}

// ---------------- predictor ----------------
__global__ __launch_bounds__(128) void pred_kernel(const float* __restrict__ h,
  const float* __restrict__ Wp1, const float* __restrict__ bp1,
  const float* __restrict__ Wp2, const float* __restrict__ bp2,
  float* __restrict__ out0)
{
  __shared__ float red[128];
  const int t = threadIdx.x;
  float s = bp1[t];
  for (int k = 0; k < HD; ++k) s = fmaf(h[k], Wp1[k*HD + t], s);
  s = fmaxf(s, 0.f) * Wp2[t];
  red[t] = s;
  __syncthreads();
  for (int off = 64; off > 0; off >>= 1){
    if (t < off) red[t] += red[t + off];
    __syncthreads();
  }
  if (t == 0) out0[0] = red[0] + bp2[0];
}

extern "C" void kernel_launch(void* const* d_in, const int* in_sizes, int n_in,
                              void* d_out, int out_size, void* d_ws, size_t ws_size,
                              hipStream_t stream)
{
  (void)out_size;
  float* fOut = (float*)d_out;
  float* predOut = fOut;               // f32[0]
  float* maskOut = fOut + 1;           // f32[1 .. 1+NE)
  float* hOut    = fOut + 1 + NE;      // f32[1+NE ..)

  // ---- env tripwire (clean since R5; kept) ----
  static const int expSizes[14] = {6400000,1200000,16384,128,49152,384,32768,128,128,1,
                                   16384,128,128,1};
  const size_t NEEDED = 87100000;
  float diag = 0.f;
  if (n_in != 14) diag = 900.f + (float)n_in;
  else {
    for (int i = 0; i < 14; ++i)
      if (in_sizes[i] != expSizes[i]){ diag = 200.f + 16.f*(float)i; break; }
  }
  if (diag == 0.f && ws_size < NEEDED) diag = 5000.f + (float)(ws_size >> 20);

  if (diag != 0.f){
    write_scalar_kernel<<<1, 1, 0, stream>>>(predOut, diag);
    return;
  }

  const float* nf   = (const float*)d_in[0];
  const void*  ei   = d_in[1];
  const float* Wemb = (const float*)d_in[2];
  const float* bemb = (const float*)d_in[3];
  const float* Wgnn = (const float*)d_in[4];
  const float* bgnn = (const float*)d_in[5];
  const float* Wm1  = (const float*)d_in[6];
  const float* bm1  = (const float*)d_in[7];
  const float* Wm2  = (const float*)d_in[8];
  const float* bm2  = (const float*)d_in[9];
  const float* Wp1  = (const float*)d_in[10];
  const float* bp1  = (const float*)d_in[11];
  const float* Wp2  = (const float*)d_in[12];
  const float* bp2  = (const float*)d_in[13];

  float* hA    = (float*)d_ws;                        // (unused)                 25.6MB
  float* tmpU  = hA   + (size_t)NN*HD;                // Ub bf16 + hB2 bf16        25.6MB
  float* Vbuf  = tmpU + (size_t)NN*HD;                // Vb bf16 + hB bf16         25.6MB
  float* srcSf = Vbuf + (size_t)NN*HD;                // srcS int                   2.4MB
  int* srcS    = (int*)srcSf;                         // NE
  int* row_start = srcS + NE;                         // NN+1
  int* cursor  = row_start + (NN + 1);                // NN (reused for Wt after fill)
  int* counts  = cursor + NN;                         // NN
  int* eids    = counts + NN;                         // NE
  int* srcW    = eids + NE;                           // NE
  int* dstW    = srcW + NE;                           // NE
  int* flag    = dstW + NE;                           // 1 (unused)
  int* partial = flag + 1;                            // NBLK

  ushort_t* Ub  = (ushort_t*)tmpU;                    // bf16 U
  ushort_t* hB2 = (ushort_t*)tmpU + (size_t)NN*HD;    // bf16 post-msg h
  ushort_t* Vb  = (ushort_t*)Vbuf;                    // bf16 V
  ushort_t* hB  = (ushort_t*)Vbuf + (size_t)NN*HD;    // bf16 pre-msg h

  // bf16 transposed weights in the cursor region (dead after fill_kernel):
  ushort_t* WtAll = (ushort_t*)cursor;
  ushort_t* WtEmb = WtAll;
  ushort_t* WtG0  = WtAll + 1*16384;
  ushort_t* WtG1  = WtAll + 2*16384;
  ushort_t* WtG2  = WtAll + 3*16384;
  ushort_t* WtU   = WtAll + 4*16384;
  ushort_t* WtV   = WtAll + 5*16384;

  // --- decode edge_index (dtype detected per-block) + dst histogram ---
  hipMemsetAsync(counts, 0, NN*sizeof(int), stream);
  extract_kernel<<<(NE + 255)/256, 256, 0, stream>>>(ei, srcW, dstW, counts);

  // --- CSR: partial sums + fused offset/local scan + fill ---
  scanA_kernel<<<NBLK, 256, 0, stream>>>(counts, partial);
  scanC_kernel<<<NBLK, 256, 0, stream>>>(counts, partial, row_start, cursor);
  fill_kernel<<<(NE + 255)/256, 256, 0, stream>>>(dstW, srcW, cursor, eids, srcS);

  // --- weight convert+transpose, single dispatch (cursor region now dead) ---
  wcvt_all_kernel<<<384, 256, 0, stream>>>(Wemb, Wgnn, Wm1, WtAll);

  // h0 = relu(nf@Wemb+bemb) -> hB bf16, + fused U/V for layer 0
  gemm_fused<1,1><<<GPERS, 256, 0, stream>>>(nf, WtEmb, bemb, nullptr, hB,
                                             WtU, WtV, bm1, Ub, Vb);

  const ushort_t* WtG[3] = {WtG0, WtG1, WtG2};
  for (int L = 0; L < 3; ++L){
    if (L < 2){
      mask_msg_kernel<0><<<NN, 128, 0, stream>>>(Ub, Vb, hB, hB2, srcS, eids,
                                                 row_start, Wm2, bm2, nullptr);
      gemm_fused<0,1><<<GPERS, 256, 0, stream>>>(hB2, WtG[L], bgnn + (size_t)L*HD,
                                                 nullptr, hB, WtU, WtV, bm1, Ub, Vb);
    } else {
      mask_msg_kernel<1><<<NN, 128, 0, stream>>>(Ub, Vb, hB, hB2, srcS, eids,
                                                 row_start, Wm2, bm2, maskOut);
      gemm_final<<<GPERS, 256, 0, stream>>>(hB2, WtG[2], bgnn + 2*HD, hOut);
    }
  }

  pred_kernel<<<1, 128, 0, stream>>>(hOut, Wp1, bp1, Wp2, bp2, predOut);
}

// Round 31
// 351.586 us; speedup vs baseline: 1.0038x; 1.0038x over previous
//
#include <hip/hip_runtime.h>
#include <hip/hip_bf16.h>

#define NN 50000
#define NE 600000
#define HD 128
#define NBLK 196                     // ceil((NN+1)/256)
#define NTILES 3125                  // NN/16 exactly
#define GPERS 782                    // persistent GEMM grid; 782*4 >= 3125
#define LDT 136                      // padded LDS row stride (ushorts)

typedef unsigned short ushort_t;
typedef __attribute__((ext_vector_type(8))) short short8v;   // 8 bf16 (4 VGPRs)
typedef __attribute__((ext_vector_type(4))) float f32x4;

__device__ __forceinline__ float sigmoidf_(float x){
  return __builtin_amdgcn_rcpf(1.f + __expf(-x));   // raw v_rcp: <=1 ulp
}

__device__ __forceinline__ ushort_t f2bf(float f){
  unsigned int u = __float_as_uint(f);
  unsigned int r = (u + 0x7FFFu + ((u >> 16) & 1u)) >> 16;   // RNE
  return (ushort_t)r;
}

__device__ __forceinline__ float bflo(unsigned u){ return __uint_as_float(u << 16); }
__device__ __forceinline__ float bfhi(unsigned u){ return __uint_as_float(u & 0xFFFF0000u); }

// ---------------- diagnostic scalar write (env tripwire) ----------------
__global__ void write_scalar_kernel(float* __restrict__ p, float v){ p[0] = v; }

// ------- edge_index decode with per-block dtype detection (+ dst histogram) --------
__global__ __launch_bounds__(256) void extract_kernel(const void* __restrict__ ei,
    int* __restrict__ srcW, int* __restrict__ dstW, int* __restrict__ counts){
  __shared__ int hasNZ;
  const int e = blockIdx.x*256 + threadIdx.x;
  if (threadIdx.x == 0) hasNZ = 0;
  __syncthreads();
  if (e < NE){
    const unsigned* w = (const unsigned*)ei;
    if (w[2*(size_t)e + 1] != 0u) hasNZ = 1;   // benign race: all writers store 1
  }
  __syncthreads();
  const bool is64 = (hasNZ == 0);
  if (e < NE){
    int s, d;
    if (is64){
      const long long* p = (const long long*)ei;
      s = (int)p[e]; d = (int)p[NE + e];
    } else {
      const int* p = (const int*)ei;
      s = p[e]; d = p[NE + e];
    }
    srcW[e] = s; dstW[e] = d;
    atomicAdd(&counts[d], 1);
  }
}

// ---------------- scan: partial sums, then fused offset+local scan ----------------
__global__ __launch_bounds__(256) void scanA_kernel(const int* __restrict__ counts,
                                                    int* __restrict__ partial){
  __shared__ int s[256];
  const int t = threadIdx.x;
  const int idx = blockIdx.x*256 + t;
  s[t] = (idx < NN) ? counts[idx] : 0;
  __syncthreads();
  for (int off = 128; off > 0; off >>= 1){
    if (t < off) s[t] += s[t + off];
    __syncthreads();
  }
  if (t == 0) partial[blockIdx.x] = s[0];
}

// scanC: block offset computed in-block from partial[] (scanB eliminated)
__global__ __launch_bounds__(256) void scanC_kernel(const int* __restrict__ counts,
    const int* __restrict__ partial, int* __restrict__ row_start, int* __restrict__ cursor){
  __shared__ int s[256];
  __shared__ int baseS;
  const int t = threadIdx.x;
  {
    int v = (t < NBLK && t < blockIdx.x) ? partial[t] : 0;
    s[t] = v;
    __syncthreads();
    for (int off = 128; off > 0; off >>= 1){
      if (t < off) s[t] += s[t + off];
      __syncthreads();
    }
    if (t == 0) baseS = s[0];
    __syncthreads();
  }
  const int base = baseS;
  __syncthreads();                     // s[] reuse
  const int idx = blockIdx.x*256 + t;
  const int c = (idx < NN) ? counts[idx] : 0;
  s[t] = c;
  __syncthreads();
  for (int off = 1; off < 256; off <<= 1){
    int add = (t >= off) ? s[t - off] : 0;
    __syncthreads();
    s[t] += add;
    __syncthreads();
  }
  const int excl = base + s[t] - c;
  if (idx < NN){ row_start[idx] = excl; cursor[idx] = excl; }
  else if (idx == NN){ row_start[NN] = excl; }
}

// fill: also writes CSR-ordered src (srcS) so msg needs no eids->srcI indirection
__global__ void fill_kernel(const int* __restrict__ dstI, const int* __restrict__ srcI,
                            int* __restrict__ cursor, int* __restrict__ eids,
                            int* __restrict__ srcS){
  int e = blockIdx.x*256 + threadIdx.x;
  if (e < NE){
    int p = atomicAdd(&cursor[dstI[e]], 1);
    eids[p] = e;
    srcS[p] = srcI[e];
  }
}

// ------- weight convert+transpose, all 6 matrices: Wt[n][k] = bf16(W[k][n]) --------
__global__ __launch_bounds__(256) void wcvt_all_kernel(const float* __restrict__ Wemb,
    const float* __restrict__ Wgnn, const float* __restrict__ Wm1,
    ushort_t* __restrict__ WtAll){
  const int idx = blockIdx.x*256 + threadIdx.x;   // 6*16384
  const int m = idx >> 14;                        // 0..5
  const int r = idx & 16383;
  const int k = r >> 7, n = r & 127;
  const float* W = (m == 0) ? Wemb : (m <= 3) ? (Wgnn + (size_t)(m-1)*16384)
                                              : (Wm1  + (size_t)(m-4)*16384);
  WtAll[(size_t)m*16384 + n*HD + k] = f2bf(W[r]);
}

// ====== persistent fused GEMM with A-prefetch across the tile loop ======
template<int F32A, int DOUV>
__global__ __launch_bounds__(256, 3) void gemm_fused(const void* __restrict__ inP,
    const ushort_t* __restrict__ Wt, const float* __restrict__ bias,
    float* __restrict__ outF, ushort_t* __restrict__ outB,
    const ushort_t* __restrict__ WtU, const ushort_t* __restrict__ WtV,
    const float* __restrict__ biasU, ushort_t* __restrict__ outU,
    ushort_t* __restrict__ outV)
{
  __shared__ ushort_t hT[16*LDT];             // 4.25 KB: block's 16x128 bf16 h tile
  const int cq   = threadIdx.x >> 6;          // col-quarter 0..3
  const int lane = threadIdx.x & 63;
  const int fr = lane & 15;
  const int fq = lane >> 4;
  short8v bh[4][2];
  #pragma unroll
  for (int ks = 0; ks < 4; ++ks)
    #pragma unroll
    for (int tcl = 0; tcl < 2; ++tcl)
      bh[ks][tcl] = *(const short8v*)(Wt + (size_t)((cq*2+tcl)*16 + fr)*HD + ks*32 + fq*8);
  short8v bu[4][2], bv[4][2];
  if (DOUV){
    #pragma unroll
    for (int ks = 0; ks < 4; ++ks)
      #pragma unroll
      for (int tcl = 0; tcl < 2; ++tcl){
        bu[ks][tcl] = *(const short8v*)(WtU + (size_t)((cq*2+tcl)*16 + fr)*HD + ks*32 + fq*8);
        bv[ks][tcl] = *(const short8v*)(WtV + (size_t)((cq*2+tcl)*16 + fr)*HD + ks*32 + fq*8);
      }
  }
  float bb[2], bub[2];
  #pragma unroll
  for (int tcl = 0; tcl < 2; ++tcl){
    const int col = (cq*2 + tcl)*16 + fr;
    bb[tcl]  = bias ? bias[col] : 0.f;
    bub[tcl] = DOUV ? biasU[col] : 0.f;
  }

  float4  aF[8];
  short8v aB[4];
  {
    const int arow = blockIdx.x*16 + fr;
    if (F32A){
      const float* in = (const float*)inP;
      #pragma unroll
      for (int ks = 0; ks < 4; ++ks){
        aF[2*ks]   = *(const float4*)(in + (size_t)arow*HD + ks*32 + fq*8);
        aF[2*ks+1] = *(const float4*)(in + (size_t)arow*HD + ks*32 + fq*8 + 4);
      }
    } else {
      const ushort_t* inB = (const ushort_t*)inP;
      #pragma unroll
      for (int ks = 0; ks < 4; ++ks)
        aB[ks] = *(const short8v*)(inB + (size_t)arow*HD + ks*32 + fq*8);
    }
  }

  #pragma unroll
  for (int it = 0; it < 4; ++it){
    const int tile = blockIdx.x + it*GPERS;
    if (tile >= NTILES) break;                 // block-uniform
    const int row0 = tile*16;
    f32x4 acc0 = (f32x4)0.0f, acc1 = (f32x4)0.0f;
    #pragma unroll
    for (int ks = 0; ks < 4; ++ks){
      short8v af;
      if (F32A){
        const float4 a0 = aF[2*ks], a1 = aF[2*ks+1];
        af[0]=(short)f2bf(a0.x); af[1]=(short)f2bf(a0.y);
        af[2]=(short)f2bf(a0.z); af[3]=(short)f2bf(a0.w);
        af[4]=(short)f2bf(a1.x); af[5]=(short)f2bf(a1.y);
        af[6]=(short)f2bf(a1.z); af[7]=(short)f2bf(a1.w);
      } else {
        af = aB[ks];
      }
      acc0 = __builtin_amdgcn_mfma_f32_16x16x32_bf16(af, bh[ks][0], acc0, 0, 0, 0);
      acc1 = __builtin_amdgcn_mfma_f32_16x16x32_bf16(af, bh[ks][1], acc1, 0, 0, 0);
    }
    {
      const int ntile = tile + GPERS;
      if (ntile < NTILES){
        const int arow = ntile*16 + fr;
        if (F32A){
          const float* in = (const float*)inP;
          #pragma unroll
          for (int ks = 0; ks < 4; ++ks){
            aF[2*ks]   = *(const float4*)(in + (size_t)arow*HD + ks*32 + fq*8);
            aF[2*ks+1] = *(const float4*)(in + (size_t)arow*HD + ks*32 + fq*8 + 4);
          }
        } else {
          const ushort_t* inB = (const ushort_t*)inP;
          #pragma unroll
          for (int ks = 0; ks < 4; ++ks)
            aB[ks] = *(const short8v*)(inB + (size_t)arow*HD + ks*32 + fq*8);
        }
      }
    }
    #pragma unroll
    for (int tcl = 0; tcl < 2; ++tcl){
      const f32x4 a = tcl ? acc1 : acc0;
      const int col = (cq*2 + tcl)*16 + fr;
      #pragma unroll
      for (int j = 0; j < 4; ++j){
        const int r = row0 + fq*4 + j;
        float x = fmaxf(a[j] + bb[tcl], 0.f);  // all h GEMMs use relu
        const ushort_t xb = f2bf(x);
        if (DOUV) hT[(fq*4 + j)*LDT + col] = xb;
        if (outF) outF[(size_t)r*HD + col] = x;
        if (outB) outB[(size_t)r*HD + col] = xb;
      }
    }
    if (DOUV){
      __syncthreads();
      f32x4 aU0 = (f32x4)0.0f, aU1 = (f32x4)0.0f;
      f32x4 aV0 = (f32x4)0.0f, aV1 = (f32x4)0.0f;
      #pragma unroll
      for (int ks = 0; ks < 4; ++ks){
        const short8v af = *(const short8v*)(hT + fr*LDT + ks*32 + fq*8);
        aU0 = __builtin_amdgcn_mfma_f32_16x16x32_bf16(af, bu[ks][0], aU0, 0, 0, 0);
        aU1 = __builtin_amdgcn_mfma_f32_16x16x32_bf16(af, bu[ks][1], aU1, 0, 0, 0);
        aV0 = __builtin_amdgcn_mfma_f32_16x16x32_bf16(af, bv[ks][0], aV0, 0, 0, 0);
        aV1 = __builtin_amdgcn_mfma_f32_16x16x32_bf16(af, bv[ks][1], aV1, 0, 0, 0);
      }
      #pragma unroll
      for (int tcl = 0; tcl < 2; ++tcl){
        const f32x4 u = tcl ? aU1 : aU0;
        const f32x4 v = tcl ? aV1 : aV0;
        const int col = (cq*2 + tcl)*16 + fr;
        #pragma unroll
        for (int j = 0; j < 4; ++j){
          const int r = row0 + fq*4 + j;
          outU[(size_t)r*HD + col] = f2bf(u[j] + bub[tcl]);
          outV[(size_t)r*HD + col] = f2bf(v[j]);
        }
      }
      __syncthreads();                         // protect hT for next iteration
    }
  }
}

// ---------------- final-layer GEMM (bf16 A -> f32 out, no UV), persistent ----------
__global__ __launch_bounds__(256, 3) void gemm_final(const ushort_t* __restrict__ inB,
    const ushort_t* __restrict__ Wt, const float* __restrict__ bias,
    float* __restrict__ outF)
{
  const int cq   = threadIdx.x >> 6;
  const int lane = threadIdx.x & 63;
  const int fr = lane & 15;
  const int fq = lane >> 4;
  short8v bh[4][2];
  #pragma unroll
  for (int ks = 0; ks < 4; ++ks)
    #pragma unroll
    for (int tcl = 0; tcl < 2; ++tcl)
      bh[ks][tcl] = *(const short8v*)(Wt + (size_t)((cq*2+tcl)*16 + fr)*HD + ks*32 + fq*8);
  float bb[2];
  #pragma unroll
  for (int tcl = 0; tcl < 2; ++tcl) bb[tcl] = bias[(cq*2 + tcl)*16 + fr];
  short8v aB[4];
  {
    const int arow = blockIdx.x*16 + fr;
    #pragma unroll
    for (int ks = 0; ks < 4; ++ks)
      aB[ks] = *(const short8v*)(inB + (size_t)arow*HD + ks*32 + fq*8);
  }
  #pragma unroll
  for (int it = 0; it < 4; ++it){
    const int tile = blockIdx.x + it*GPERS;
    if (tile >= NTILES) break;
    const int row0 = tile*16;
    f32x4 acc0 = (f32x4)0.0f, acc1 = (f32x4)0.0f;
    #pragma unroll
    for (int ks = 0; ks < 4; ++ks){
      acc0 = __builtin_amdgcn_mfma_f32_16x16x32_bf16(aB[ks], bh[ks][0], acc0, 0, 0, 0);
      acc1 = __builtin_amdgcn_mfma_f32_16x16x32_bf16(aB[ks], bh[ks][1], acc1, 0, 0, 0);
    }
    const int ntile = tile + GPERS;
    if (ntile < NTILES){
      const int arow = ntile*16 + fr;
      #pragma unroll
      for (int ks = 0; ks < 4; ++ks)
        aB[ks] = *(const short8v*)(inB + (size_t)arow*HD + ks*32 + fq*8);
    }
    #pragma unroll
    for (int tcl = 0; tcl < 2; ++tcl){
      const f32x4 a = tcl ? acc1 : acc0;
      const int col = (cq*2 + tcl)*16 + fr;
      #pragma unroll
      for (int j = 0; j < 4; ++j){
        const int r = row0 + fq*4 + j;
        outF[(size_t)r*HD + col] = fmaxf(a[j] + bb[tcl], 0.f);
      }
    }
  }
}

// ------------- fused mask+msg, templated on mask-scatter, 2-deep pipeline ----------
template<int MASKW>
__global__ __launch_bounds__(256) void mask_msg_kernel(
    const ushort_t* __restrict__ U, const ushort_t* __restrict__ V,
    const ushort_t* __restrict__ hB,        // gather source + own-row base (bf16)
    ushort_t* __restrict__ hB2,             // out: bf16 of post-msg h
    const int* __restrict__ srcS, const int* __restrict__ eidS,
    const int* __restrict__ row_start,
    const float* __restrict__ Wm2, const float* __restrict__ bm2,
    float* __restrict__ maskOut)            // used only when MASKW
{
  const int v = blockIdx.x*4 + (threadIdx.x >> 6);
  const int lane = threadIdx.x & 63;
  const int g   = lane >> 4;                // edge group 0..3
  const int sub = lane & 15;                // lane in group
  const float4 wA = ((const float4*)Wm2)[sub*2];      // cols sub*8..+3
  const float4 wB = ((const float4*)Wm2)[sub*2+1];    // cols sub*8+4..+7
  const float b2 = bm2[0];
  const uint4 vv = ((const uint4*)(V + (size_t)v*HD))[sub];
  float a0=0.f,a1=0.f,a2=0.f,a3=0.f,a4=0.f,a5=0.f,a6=0.f,a7=0.f;
  const int beg = row_start[v], end = row_start[v+1];
  int idx = beg + g;
  uint4 uu = make_uint4(0,0,0,0), hh = make_uint4(0,0,0,0);
  int e0 = 0;
  if (idx < end){
    const int s = srcS[idx];
    if (MASKW) e0 = eidS[idx];
    uu = ((const uint4*)(U  + (size_t)s*HD))[sub];
    hh = ((const uint4*)(hB + (size_t)s*HD))[sub];
  }
  while (idx < end){
    const int nidx = idx + 4;
    uint4 uuN = make_uint4(0,0,0,0), hhN = make_uint4(0,0,0,0);
    int eN = 0;
    if (nidx < end){
      const int sn = srcS[nidx];
      if (MASKW) eN = eidS[nidx];
      uuN = ((const uint4*)(U  + (size_t)sn*HD))[sub];
      hhN = ((const uint4*)(hB + (size_t)sn*HD))[sub];
    }
    float p;
    p = fmaxf(bflo(uu.x)+bflo(vv.x), 0.f) * wA.x;
    p = fmaf(fmaxf(bfhi(uu.x)+bfhi(vv.x), 0.f), wA.y, p);
    p = fmaf(fmaxf(bflo(uu.y)+bflo(vv.y), 0.f), wA.z, p);
    p = fmaf(fmaxf(bfhi(uu.y)+bfhi(vv.y), 0.f), wA.w, p);
    p = fmaf(fmaxf(bflo(uu.z)+bflo(vv.z), 0.f), wB.x, p);
    p = fmaf(fmaxf(bfhi(uu.z)+bfhi(vv.z), 0.f), wB.y, p);
    p = fmaf(fmaxf(bflo(uu.w)+bflo(vv.w), 0.f), wB.z, p);
    p = fmaf(fmaxf(bfhi(uu.w)+bfhi(vv.w), 0.f), wB.w, p);
    p += __shfl_xor(p, 1, 64);
    p += __shfl_xor(p, 2, 64);
    p += __shfl_xor(p, 4, 64);
    p += __shfl_xor(p, 8, 64);
    const float imp = sigmoidf_(p + b2);
    const float mk  = sigmoidf_((imp - 0.4f) * 2.0f);
    if (MASKW && sub == 0) maskOut[e0] = mk;
    a0 = fmaf(mk, bflo(hh.x), a0);
    a1 = fmaf(mk, bfhi(hh.x), a1);
    a2 = fmaf(mk, bflo(hh.y), a2);
    a3 = fmaf(mk, bfhi(hh.y), a3);
    a4 = fmaf(mk, bflo(hh.z), a4);
    a5 = fmaf(mk, bfhi(hh.z), a5);
    a6 = fmaf(mk, bflo(hh.w), a6);
    a7 = fmaf(mk, bfhi(hh.w), a7);
    uu = uuN; hh = hhN; e0 = eN; idx = nidx;
  }
  a0 += __shfl_xor(a0, 16, 64); a0 += __shfl_xor(a0, 32, 64);
  a1 += __shfl_xor(a1, 16, 64); a1 += __shfl_xor(a1, 32, 64);
  a2 += __shfl_xor(a2, 16, 64); a2 += __shfl_xor(a2, 32, 64);
  a3 += __shfl_xor(a3, 16, 64); a3 += __shfl_xor(a3, 32, 64);
  a4 += __shfl_xor(a4, 16, 64); a4 += __shfl_xor(a4, 32, 64);
  a5 += __shfl_xor(a5, 16, 64); a5 += __shfl_xor(a5, 32, 64);
  a6 += __shfl_xor(a6, 16, 64); a6 += __shfl_xor(a6, 32, 64);
  a7 += __shfl_xor(a7, 16, 64); a7 += __shfl_xor(a7, 32, 64);
  if (g == 0){
    const uint4 hrow = ((const uint4*)(hB + (size_t)v*HD))[sub];  // own row, bf16
    const float x0 = bflo(hrow.x) + a0, x1 = bfhi(hrow.x) + a1;
    const float x2 = bflo(hrow.y) + a2, x3 = bfhi(hrow.y) + a3;
    const float x4 = bflo(hrow.z) + a4, x5 = bfhi(hrow.z) + a5;
    const float x6 = bflo(hrow.w) + a6, x7 = bfhi(hrow.w) + a7;
    ushort4 p0, p1;
    p0.x = f2bf(x0); p0.y = f2bf(x1); p0.z = f2bf(x2); p0.w = f2bf(x3);
    p1.x = f2bf(x4); p1.y = f2bf(x5); p1.z = f2bf(x6); p1.w = f2bf(x7);
    ushort4* hb2row = (ushort4*)(hB2 + (size_t)v*HD) + sub*2;
    hb2row[0] = p0;
    hb2row[1] = p1;
  }
}

// ---------------- predictor ----------------
__global__ __launch_bounds__(128) void pred_kernel(const float* __restrict__ h,
  const float* __restrict__ Wp1, const float* __restrict__ bp1,
  const float* __restrict__ Wp2, const float* __restrict__ bp2,
  float* __restrict__ out0)
{
  __shared__ float red[128];
  const int t = threadIdx.x;
  float s = bp1[t];
  for (int k = 0; k < HD; ++k) s = fmaf(h[k], Wp1[k*HD + t], s);
  s = fmaxf(s, 0.f) * Wp2[t];
  red[t] = s;
  __syncthreads();
  for (int off = 64; off > 0; off >>= 1){
    if (t < off) red[t] += red[t + off];
    __syncthreads();
  }
  if (t == 0) out0[0] = red[0] + bp2[0];
}

extern "C" void kernel_launch(void* const* d_in, const int* in_sizes, int n_in,
                              void* d_out, int out_size, void* d_ws, size_t ws_size,
                              hipStream_t stream)
{
  (void)out_size;
  float* fOut = (float*)d_out;
  float* predOut = fOut;               // f32[0]
  float* maskOut = fOut + 1;           // f32[1 .. 1+NE)
  float* hOut    = fOut + 1 + NE;      // f32[1+NE ..)

  // ---- env tripwire (clean since R5; kept) ----
  static const int expSizes[14] = {6400000,1200000,16384,128,49152,384,32768,128,128,1,
                                   16384,128,128,1};
  const size_t NEEDED = 87100000;
  float diag = 0.f;
  if (n_in != 14) diag = 900.f + (float)n_in;
  else {
    for (int i = 0; i < 14; ++i)
      if (in_sizes[i] != expSizes[i]){ diag = 200.f + 16.f*(float)i; break; }
  }
  if (diag == 0.f && ws_size < NEEDED) diag = 5000.f + (float)(ws_size >> 20);

  if (diag != 0.f){
    write_scalar_kernel<<<1, 1, 0, stream>>>(predOut, diag);
    return;
  }

  const float* nf   = (const float*)d_in[0];
  const void*  ei   = d_in[1];
  const float* Wemb = (const float*)d_in[2];
  const float* bemb = (const float*)d_in[3];
  const float* Wgnn = (const float*)d_in[4];
  const float* bgnn = (const float*)d_in[5];
  const float* Wm1  = (const float*)d_in[6];
  const float* bm1  = (const float*)d_in[7];
  const float* Wm2  = (const float*)d_in[8];
  const float* bm2  = (const float*)d_in[9];
  const float* Wp1  = (const float*)d_in[10];
  const float* bp1  = (const float*)d_in[11];
  const float* Wp2  = (const float*)d_in[12];
  const float* bp2  = (const float*)d_in[13];

  float* hA    = (float*)d_ws;                        // (unused)                 25.6MB
  float* tmpU  = hA   + (size_t)NN*HD;                // Ub bf16 + hB2 bf16        25.6MB
  float* Vbuf  = tmpU + (size_t)NN*HD;                // Vb bf16 + hB bf16         25.6MB
  float* srcSf = Vbuf + (size_t)NN*HD;                // srcS int                   2.4MB
  int* srcS    = (int*)srcSf;                         // NE
  int* row_start = srcS + NE;                         // NN+1
  int* cursor  = row_start + (NN + 1);                // NN (reused for Wt after fill)
  int* counts  = cursor + NN;                         // NN
  int* eids    = counts + NN;                         // NE
  int* srcW    = eids + NE;                           // NE
  int* dstW    = srcW + NE;                           // NE
  int* flag    = dstW + NE;                           // 1 (unused)
  int* partial = flag + 1;                            // NBLK

  ushort_t* Ub  = (ushort_t*)tmpU;                    // bf16 U
  ushort_t* hB2 = (ushort_t*)tmpU + (size_t)NN*HD;    // bf16 post-msg h
  ushort_t* Vb  = (ushort_t*)Vbuf;                    // bf16 V
  ushort_t* hB  = (ushort_t*)Vbuf + (size_t)NN*HD;    // bf16 pre-msg h

  // bf16 transposed weights in the cursor region (dead after fill_kernel):
  ushort_t* WtAll = (ushort_t*)cursor;
  ushort_t* WtEmb = WtAll;
  ushort_t* WtG0  = WtAll + 1*16384;
  ushort_t* WtG1  = WtAll + 2*16384;
  ushort_t* WtG2  = WtAll + 3*16384;
  ushort_t* WtU   = WtAll + 4*16384;
  ushort_t* WtV   = WtAll + 5*16384;

  // --- decode edge_index (dtype detected per-block) + dst histogram ---
  hipMemsetAsync(counts, 0, NN*sizeof(int), stream);
  extract_kernel<<<(NE + 255)/256, 256, 0, stream>>>(ei, srcW, dstW, counts);

  // --- CSR: partial sums + fused offset/local scan + fill ---
  scanA_kernel<<<NBLK, 256, 0, stream>>>(counts, partial);
  scanC_kernel<<<NBLK, 256, 0, stream>>>(counts, partial, row_start, cursor);
  fill_kernel<<<(NE + 255)/256, 256, 0, stream>>>(dstW, srcW, cursor, eids, srcS);

  // --- weight convert+transpose, single dispatch (cursor region now dead) ---
  wcvt_all_kernel<<<384, 256, 0, stream>>>(Wemb, Wgnn, Wm1, WtAll);

  // h0 = relu(nf@Wemb+bemb) -> hB bf16, + fused U/V for layer 0
  gemm_fused<1,1><<<GPERS, 256, 0, stream>>>(nf, WtEmb, bemb, nullptr, hB,
                                             WtU, WtV, bm1, Ub, Vb);

  const ushort_t* WtG[3] = {WtG0, WtG1, WtG2};
  for (int L = 0; L < 3; ++L){
    if (L < 2){
      mask_msg_kernel<0><<<NN/4, 256, 0, stream>>>(Ub, Vb, hB, hB2, srcS, eids,
                                                   row_start, Wm2, bm2, nullptr);
      gemm_fused<0,1><<<GPERS, 256, 0, stream>>>(hB2, WtG[L], bgnn + (size_t)L*HD,
                                                 nullptr, hB, WtU, WtV, bm1, Ub, Vb);
    } else {
      mask_msg_kernel<1><<<NN/4, 256, 0, stream>>>(Ub, Vb, hB, hB2, srcS, eids,
                                                   row_start, Wm2, bm2, maskOut);
      gemm_final<<<GPERS, 256, 0, stream>>>(hB2, WtG[2], bgnn + 2*HD, hOut);
    }
  }

  pred_kernel<<<1, 128, 0, stream>>>(hOut, Wp1, bp1, Wp2, bp2, predOut);
}